// Round 2
// baseline (319.432 us; speedup 1.0000x reference)
//
#include <hip/hip_runtime.h>
#include <cmath>

// INGP hashgrid encode, two-kernel (R3 structure) + x-pair merged gathers.
//   Gather: level pinned per XCD (blockIdx%8; phase2 lvl=15-k) -> XCD's 4MiB
//   L2 holds its level's table. Fitted model: distinct-line-miss bound,
//   ~3.9us per M line-misses (R6: removing point-line traffic was neutral ->
//   table misses are the critical resource). So we REDUCE table line-misses:
//   - corners (0,j,k)/(1,j,k) have idx h and h^1 when ix is even -> one
//     aligned float4 load covers both (hashed path: avg 6 lines/pt-level).
//   - R7: levels 0-4 use DENSE memoized tables (prep kernel copies
//     table[hash(cell)] into a dense grid, 2x2x2-blocked so one cell block
//     = one 64B line). Corners span (1+px)(1+py)(1+pz) blocks -> avg 3.375
//     lines/pt-level, plus L1 hits (l0-l2 footprints 47-262KB). Bitwise
//     identical output (pure memoization of the same hash).
//   R5 lesson: cross-XCD partial-line output stores are catastrophic ->
//   keep level-major ws + LDS-tile transpose.

constexpr int LVLS = 16;
constexpr int NDENSE = 5;            // levels 0..4 dense (r=16,22,30,42,58)
constexpr unsigned TBL = 1u << 19;
constexpr unsigned TMASK = TBL - 1u;
constexpr unsigned P1 = 2654435761u;
constexpr unsigned P2 = 805459861u;
constexpr int PTS_PER_BLOCK = 512;   // 256 threads x 2 points

typedef float vf2 __attribute__((ext_vector_type(2)));
typedef float vf4 __attribute__((ext_vector_type(4)));

struct LvlCfg {
    float r[LVLS];
    int doff[LVLS];   // dense offset (float2 entries); only 0..NDENSE-1 used
    int dBy[LVLS];    // blocks per y dim
    int dBz[LVLS];    // blocks per z dim
};

// Fill dense mirror tables: dense[off[l] + e] = table[l][hash(cell(e)) & mask].
// Blocked layout: entry e = (((bx*By)+by)*Bz+bz)*8 + (cx&1)*4+(cy&1)*2+(cz&1).
// Note R=r+1 is odd for all dense levels, so the pad coord 2*B-1 == r+1 covers
// the tie-rounding edge (pos rounding up to exactly r at r=2^k).
__global__ __launch_bounds__(256) void ingp_prep(
    const float* __restrict__ tables, float2* __restrict__ dense,
    LvlCfg cfg, int total)
{
    int i = blockIdx.x * 256 + threadIdx.x;
    if (i >= total) return;
    int l = 0, off = cfg.doff[0], By = cfg.dBy[0], Bz = cfg.dBz[0];
    #pragma unroll
    for (int k = 1; k < NDENSE; ++k)
        if (i >= cfg.doff[k]) { l = k; off = cfg.doff[k]; By = cfg.dBy[k]; Bz = cfg.dBz[k]; }
    int e = i - off;
    int sub = e & 7, blk = e >> 3;
    int bz = blk % Bz; int tmp = blk / Bz;
    int by = tmp % By; int bx = tmp / By;
    unsigned cx = (unsigned)(bx * 2 + ((sub >> 2) & 1));
    unsigned cy = (unsigned)(by * 2 + ((sub >> 1) & 1));
    unsigned cz = (unsigned)(bz * 2 + (sub & 1));
    unsigned h = cx ^ (cy * P1) ^ (cz * P2);
    const float2* tab = (const float2*)tables + (size_t)l * TBL;
    dense[i] = tab[h & TMASK];
}

template<bool USE_WS>
__global__ __launch_bounds__(256) void ingp_gather(
    const float* __restrict__ pts,
    const float* __restrict__ tables,
    const float2* __restrict__ dense,
    float2* __restrict__ dst,     // USE_WS: [L][N] float2 ; else [N][L] float2
    LvlCfg cfg, int npts, int bpl, int ndense)
{
    __shared__ float s_res[LVLS];
    __shared__ int s_doff[LVLS], s_dBy[LVLS], s_dBz[LVLS];
    __shared__ float s_pts[PTS_PER_BLOCK * 3];
    if (threadIdx.x < LVLS) {
        s_res[threadIdx.x]  = cfg.r[threadIdx.x];
        s_doff[threadIdx.x] = cfg.doff[threadIdx.x];
        s_dBy[threadIdx.x]  = cfg.dBy[threadIdx.x];
        s_dBz[threadIdx.x]  = cfg.dBz[threadIdx.x];
    }

    int b = blockIdx.x;
    int phase_blocks = 8 * bpl;
    int xcd = b & 7;
    int phase = b / phase_blocks;
    int lvl = phase == 0 ? xcd : 15 - xcd;   // balanced pairing (k, 15-k)
    int q = (b % phase_blocks) >> 3;
    int t = threadIdx.x;

    // Stage this block's 512 points into LDS (coalesced nt dword loads).
    {
        int base_dw = q * PTS_PER_BLOCK * 3;
        int total_dw = npts * 3 - base_dw;   // >0 for every launched block
        const float* src = pts + base_dw;
        #pragma unroll
        for (int k = 0; k < 6; ++k) {
            int i = t + k * 256;
            float v = 0.f;
            if (i < total_dw) v = __builtin_nontemporal_load(src + i);
            s_pts[i] = v;
        }
    }
    __syncthreads();

    float r = s_res[lvl];
    bool dense_lvl = lvl < ndense;
    const float2* __restrict__ tab = (const float2*)tables + (size_t)lvl * TBL;
    const float2* __restrict__ dtab = dense + (dense_lvl ? s_doff[lvl] : 0);
    unsigned By = dense_lvl ? (unsigned)s_dBy[lvl] : 1u;
    unsigned Bz = dense_lvl ? (unsigned)s_dBz[lvl] : 1u;

    int p0 = q * PTS_PER_BLOCK + t;

    #pragma unroll
    for (int s = 0; s < 2; ++s) {
        int lp = t + s * 256;          // local point index in LDS
        int pglob = p0 + s * 256;      // global point index
        bool valid = pglob < npts;
        float px = s_pts[lp * 3 + 0];
        float py = s_pts[lp * 3 + 1];
        float pz = s_pts[lp * 3 + 2];
        float x = (px + 1.0f) * 0.5f;
        float y = (py + 1.0f) * 0.5f;
        float z = (pz + 1.0f) * 0.5f;
        float posx = x * r, posy = y * r, posz = z * r;
        float fx = floorf(posx), fy = floorf(posy), fz = floorf(posz);
        float wx = posx - fx, wy = posy - fy, wz = posz - fz;
        unsigned ix = (unsigned)fx, iy = (unsigned)fy, iz = (unsigned)fz;

        // v[i*4 + j*2 + k]: corner (i,j,k)
        float2 v[8];

        if (dense_lvl) {
            // Dense 2x2x2-line-blocked mirror table.
            unsigned bx0 = ix >> 1, pxb = ix & 1u;
            unsigned by0 = iy >> 1, pyb = iy & 1u;
            unsigned bz0 = iz >> 1, pzb = iz & 1u;
            unsigned rx0 = bx0 * By;
            unsigned rx1 = (bx0 + pxb) * By;
            unsigned r00 = (rx0 + by0) * Bz;
            unsigned r01 = (rx0 + by0 + pyb) * Bz;
            unsigned r10 = (rx1 + by0) * Bz;
            unsigned r11 = (rx1 + by0 + pyb) * Bz;
            unsigned x0 = pxb * 4u, x1 = 4u - x0;   // X(i)*4
            unsigned y0 = pyb * 2u, y1 = 2u - y0;   // Y(j)*2
            unsigned s00 = x0 + y0, s01 = x0 + y1, s10 = x1 + y0, s11 = x1 + y1;
            if (pzb == 0u) {
                // both z-corners adjacent in one block -> aligned float4
                unsigned e00 = (r00 + bz0) * 8u + s00;
                unsigned e01 = (r01 + bz0) * 8u + s01;
                unsigned e10 = (r10 + bz0) * 8u + s10;
                unsigned e11 = (r11 + bz0) * 8u + s11;
                vf4 q0 = *(const vf4*)(dtab + e00);
                vf4 q1 = *(const vf4*)(dtab + e01);
                vf4 q2 = *(const vf4*)(dtab + e10);
                vf4 q3 = *(const vf4*)(dtab + e11);
                v[0] = make_float2(q0.x, q0.y); v[1] = make_float2(q0.z, q0.w);
                v[2] = make_float2(q1.x, q1.y); v[3] = make_float2(q1.z, q1.w);
                v[4] = make_float2(q2.x, q2.y); v[5] = make_float2(q2.z, q2.w);
                v[6] = make_float2(q3.x, q3.y); v[7] = make_float2(q3.z, q3.w);
            } else {
                unsigned bzA = bz0, bzB = bz0 + 1u;  // k=0: (bzA,Z=1); k=1: (bzB,Z=0)
                v[0] = dtab[(r00 + bzA) * 8u + s00 + 1u];
                v[1] = dtab[(r00 + bzB) * 8u + s00];
                v[2] = dtab[(r01 + bzA) * 8u + s01 + 1u];
                v[3] = dtab[(r01 + bzB) * 8u + s01];
                v[4] = dtab[(r10 + bzA) * 8u + s10 + 1u];
                v[5] = dtab[(r10 + bzB) * 8u + s10];
                v[6] = dtab[(r11 + bzA) * 8u + s11 + 1u];
                v[7] = dtab[(r11 + bzB) * 8u + s11];
            }
        } else {
            unsigned hx0 = ix,      hx1 = ix + 1u;
            unsigned hy0 = iy * P1;
            unsigned hz0 = iz * P2, hz1 = hz0 + P2;
            unsigned hyz[4];
            hyz[0] = hy0 ^ hz0;
            hyz[1] = hy0 ^ hz1;
            hyz[2] = (hy0 + P1) ^ hz0;
            hyz[3] = (hy0 + P1) ^ hz1;

            if ((ix & 1u) == 0u) {
                // x-pair idx differ by ^1 -> one aligned float4 covers both.
                #pragma unroll
                for (int yz = 0; yz < 4; ++yz) {
                    unsigned b0 = (hx0 ^ hyz[yz]) & TMASK;   // x=0 corner
                    const vf4* lp4 = (const vf4*)(tab + (b0 & ~1u));
                    vf4 qd = *lp4;
                    float2 lo = make_float2(qd.x, qd.y);
                    float2 hi = make_float2(qd.z, qd.w);
                    bool odd = (b0 & 1u) != 0u;
                    v[yz]     = odd ? hi : lo;   // x=0 corner
                    v[4 + yz] = odd ? lo : hi;   // x=1 corner (idx = b0^1)
                }
            } else {
                #pragma unroll
                for (int yz = 0; yz < 4; ++yz) {
                    unsigned b0 = (hx0 ^ hyz[yz]) & TMASK;
                    unsigned b1 = (hx1 ^ hyz[yz]) & TMASK;
                    v[yz]     = tab[b0];
                    v[4 + yz] = tab[b1];
                }
            }
        }

        float ox = 1.0f - wx, oy = 1.0f - wy, oz = 1.0f - wz;
        float w[8];
        w[0] = (ox * oy) * oz;   // (0,0,0)
        w[1] = (ox * oy) * wz;   // (0,0,1)
        w[2] = (ox * wy) * oz;   // (0,1,0)
        w[3] = (ox * wy) * wz;   // (0,1,1)
        w[4] = (wx * oy) * oz;   // (1,0,0)
        w[5] = (wx * oy) * wz;   // (1,0,1)
        w[6] = (wx * wy) * oz;   // (1,1,0)
        w[7] = (wx * wy) * wz;   // (1,1,1)

        float f0 = w[0] * v[0].x;
        float f1 = w[0] * v[0].y;
        #pragma unroll
        for (int c = 1; c < 8; ++c) {
            f0 += w[c] * v[c].x;
            f1 += w[c] * v[c].y;
        }
        if (valid) {
            vf2 o; o.x = f0; o.y = f1;
            if (USE_WS)
                __builtin_nontemporal_store(o, (vf2*)(dst + (size_t)lvl * npts + pglob));
            else
                dst[(size_t)pglob * LVLS + lvl] = make_float2(f0, f1);
        }
    }
}

// ws [L][N] float2  ->  out [N][L] float2, all-coalesced via LDS tile.
__global__ __launch_bounds__(256) void ingp_transpose(
    const float2* __restrict__ ws, float4* __restrict__ out, int npts)
{
    __shared__ float2 a[LVLS][258];
    int base = blockIdx.x * 256;
    int t = threadIdx.x;

    #pragma unroll
    for (int l = 0; l < LVLS; ++l) {
        int pp = base + t;
        float2 val = make_float2(0.f, 0.f);
        if (pp < npts) {
            vf2 v = __builtin_nontemporal_load((const vf2*)(ws + (size_t)l * npts + pp));
            val = make_float2(v.x, v.y);
        }
        a[l][t] = val;
    }
    __syncthreads();

    int j = t & 7;
    int pl = t >> 3;
    #pragma unroll
    for (int it = 0; it < 8; ++it) {
        int pt = pl + it * 32;
        if (base + pt < npts) {
            float2 u = a[2 * j][pt];
            float2 v = a[2 * j + 1][pt];
            vf4 o; o.x = u.x; o.y = u.y; o.z = v.x; o.w = v.y;
            __builtin_nontemporal_store(o, (vf4*)(out + (size_t)(base + pt) * 8 + j));
        }
    }
}

extern "C" void kernel_launch(void* const* d_in, const int* in_sizes, int n_in,
                              void* d_out, int out_size, void* d_ws, size_t ws_size,
                              hipStream_t stream) {
    const float* pts    = (const float*)d_in[0];
    const float* tables = (const float*)d_in[1];
    int npts = in_sizes[0] / 3;

    // numpy-bitwise RES: GROWTH = exp((log(2048)-log(16))/15); floor(16*G**l)
    LvlCfg cfg;
    double growth = exp((log(2048.0) - log(16.0)) / 15.0);
    int cum = 0;
    for (int l = 0; l < LVLS; ++l) {
        cfg.r[l] = (float)floor(16.0 * pow(growth, (double)l));
        cfg.doff[l] = 0; cfg.dBy[l] = 1; cfg.dBz[l] = 1;
        if (l < NDENSE) {
            int R = (int)cfg.r[l] + 1;        // corner coords 0..r (R odd)
            int B = (R + 1) >> 1;             // blocks/dim; pad coord = r+1
            cfg.doff[l] = cum;
            cfg.dBy[l] = B; cfg.dBz[l] = B;
            cum += 8 * B * B * B;             // float2 entries this level
        }
    }
    size_t dense_bytes = (size_t)cum * sizeof(float2);

    int bpl = (npts + PTS_PER_BLOCK - 1) / PTS_PER_BLOCK;
    int grid = LVLS * bpl;

    size_t ws_needed = (size_t)LVLS * npts * sizeof(float2);
    bool use_ws = ws_size >= ws_needed;
    bool use_dense = use_ws && (ws_size >= ws_needed + dense_bytes);

    float2* dense = use_dense ? (float2*)((char*)d_ws + ws_needed) : nullptr;
    int ndense = use_dense ? NDENSE : 0;

    if (use_dense) {
        int pgrid = (cum + 255) / 256;
        hipLaunchKernelGGL(ingp_prep, dim3(pgrid), dim3(256), 0, stream,
                           tables, dense, cfg, cum);
    }

    if (use_ws) {
        float2* ws = (float2*)d_ws;
        hipLaunchKernelGGL(ingp_gather<true>, dim3(grid), dim3(256), 0, stream,
                           pts, tables, dense, ws, cfg, npts, bpl, ndense);
        hipLaunchKernelGGL(ingp_transpose, dim3((npts + 255) / 256), dim3(256), 0, stream,
                           ws, (float4*)d_out, npts);
    } else {
        hipLaunchKernelGGL(ingp_gather<false>, dim3(grid), dim3(256), 0, stream,
                           pts, tables, dense, (float2*)d_out, cfg, npts, bpl, ndense);
    }
}